// Round 1
// baseline (1290.034 us; speedup 1.0000x reference)
//
#include <hip/hip_runtime.h>
#include <math.h>

// Problem constants (B=2, S=2048, D=1024, H=16, hd=64, K=16)
#define SEQ 2048
#define DIM 1024
#define NB  2
#define NH  16

__device__ __forceinline__ float dot4(float4 a, float4 b) {
    return a.x*b.x + a.y*b.y + a.z*b.z + a.w*b.w;
}
__device__ __forceinline__ void fma4(float4& a, float s, float4 b) {
    a.x = fmaf(s, b.x, a.x); a.y = fmaf(s, b.y, a.y);
    a.z = fmaf(s, b.z, a.z); a.w = fmaf(s, b.w, a.w);
}

// ---------------------------------------------------------------------------
// K1: per-diff stats: sbuf = tanh(|x[j+1]-x[j]|), invbuf = 1/max(|.|,1e-8)
// one wave per diff row
// ---------------------------------------------------------------------------
__global__ __launch_bounds__(256) void traj_stats_kernel(
    const float* __restrict__ x, float* __restrict__ sbuf, float* __restrict__ invbuf)
{
    const int wave = threadIdx.x >> 6;
    const int lane = threadIdx.x & 63;
    const int row  = blockIdx.x * 4 + wave;     // b*(S-1)+j
    const int NR = NB * (SEQ - 1);
    if (row >= NR) return;
    const int b = row / (SEQ - 1);
    const int j = row - b * (SEQ - 1);
    const float* x0 = x + ((size_t)(b * SEQ + j)) * DIM;
    const float* x1 = x0 + DIM;
    float sum = 0.f;
    #pragma unroll
    for (int q = 0; q < 4; ++q) {
        int idx = q * 256 + lane * 4;
        float4 a = *(const float4*)(x0 + idx);
        float4 c = *(const float4*)(x1 + idx);
        float dx = c.x-a.x, dy = c.y-a.y, dz = c.z-a.z, dw = c.w-a.w;
        sum += dx*dx + dy*dy + dz*dz + dw*dw;
    }
    #pragma unroll
    for (int off = 32; off > 0; off >>= 1) sum += __shfl_down(sum, off);
    if (lane == 0) {
        float mag = sqrtf(sum);
        sbuf[row]   = tanhf(mag);
        invbuf[row] = 1.0f / fmaxf(mag, 1e-8f);
    }
}

// ---------------------------------------------------------------------------
// K2: traj[b,p,:] = sum_{j in window} nw * (x[j+1]-x[j]) * inv_mag
// one block per (b,p); window <= 8
// ---------------------------------------------------------------------------
__global__ __launch_bounds__(256) void traj_kernel(
    const float* __restrict__ x, const float* __restrict__ sbuf,
    const float* __restrict__ invbuf, float* __restrict__ traj_out)
{
    const int bp = blockIdx.x;
    const int b  = bp >> 11;
    const int p  = bp & (SEQ - 1);
    int ws = p - 8; if (ws < 0) ws = 0;
    const int wlen = p - ws;
    const float wsz = (float)((p - ws) > 1 ? (p - ws) : 1);
    const int base = b * (SEQ - 1) + ws;

    float Z = 0.f;
    for (int t = 0; t < wlen; ++t)
        Z += sbuf[base + t] * ((float)(t + 1) / wsz);
    const float scale = 1.0f / fmaxf(Z, 1e-8f);

    const int d0 = threadIdx.x * 4;
    const float* xb = x + ((size_t)(b * SEQ + ws)) * DIM + d0;
    float4 prev = *(const float4*)xb;
    float4 acc = make_float4(0.f,0.f,0.f,0.f);
    for (int t = 0; t < wlen; ++t) {
        xb += DIM;
        float4 cur = *(const float4*)xb;
        float cc = sbuf[base + t] * ((float)(t + 1) / wsz) * invbuf[base + t] * scale;
        acc.x += cc * (cur.x - prev.x);
        acc.y += cc * (cur.y - prev.y);
        acc.z += cc * (cur.z - prev.z);
        acc.w += cc * (cur.w - prev.w);
        prev = cur;
    }
    *(float4*)(traj_out + (size_t)bp * DIM + d0) = acc;
}

// ---------------------------------------------------------------------------
// K3/K6: C = A[Mx1024] @ W[Nx1024]^T, 128x128 tiles, Kt=32, 8x8 micro.
// MODE 0: plain store to cout (ldc). MODE 1 (qkv fused):
//   n0 in [0,1024)    -> q: fused splat-weight epilogue -> qwbuf
//   n0 in [1024,2048) -> k: same -> kwbuf
//   n0 in [2048,3072) -> v: store [B,S,D] layout -> vbuf
// ---------------------------------------------------------------------------
template<int MODE>
__global__ __launch_bounds__(256) void gemm_kernel(
    const float* __restrict__ A, const float* __restrict__ W,
    float* __restrict__ cout, int ldc,
    float* __restrict__ vbuf, float* __restrict__ qwbuf, float* __restrict__ kwbuf,
    const float* __restrict__ centers, const float* __restrict__ lscales,
    const float* __restrict__ amps)
{
    __shared__ float lds[8704];           // staging 2*32*132=8448; epilogue Cs 128*68=8704
    const int tid = threadIdx.x;
    const int n0 = blockIdx.x * 128;
    const int m0 = blockIdx.y * 128;
    float* As = lds;
    float* Bs = lds + 4224;
    const int rg = tid & 15;
    const int tn = tid >> 4;
    const int ra = rg * 4;
    const int ca = tn * 4;

    float4 acc[2][8];
    #pragma unroll
    for (int i = 0; i < 2; ++i)
        #pragma unroll
        for (int j = 0; j < 8; ++j) acc[i][j] = make_float4(0.f,0.f,0.f,0.f);

    for (int kb = 0; kb < 1024; kb += 32) {
        #pragma unroll
        for (int i = 0; i < 4; ++i) {
            int L = tid + i * 256;
            int row = L >> 3;
            int c4 = (L & 7) * 4;
            float4 va = *(const float4*)(A + (size_t)(m0 + row) * 1024 + kb + c4);
            float4 vb = *(const float4*)(W + (size_t)(n0 + row) * 1024 + kb + c4);
            As[(c4+0)*132 + row] = va.x;
            As[(c4+1)*132 + row] = va.y;
            As[(c4+2)*132 + row] = va.z;
            As[(c4+3)*132 + row] = va.w;
            Bs[(c4+0)*132 + row] = vb.x;
            Bs[(c4+1)*132 + row] = vb.y;
            Bs[(c4+2)*132 + row] = vb.z;
            Bs[(c4+3)*132 + row] = vb.w;
        }
        __syncthreads();
        #pragma unroll 8
        for (int kk = 0; kk < 32; ++kk) {
            const float* Ak = As + kk*132;
            const float* Bk = Bs + kk*132;
            float4 a0 = *(const float4*)(Ak + ra);
            float4 a1 = *(const float4*)(Ak + ra + 64);
            float4 b0 = *(const float4*)(Bk + ca);
            float4 b1 = *(const float4*)(Bk + ca + 64);
            float as[8] = {a0.x,a0.y,a0.z,a0.w,a1.x,a1.y,a1.z,a1.w};
            #pragma unroll
            for (int r = 0; r < 8; ++r) {
                fma4(acc[0][r], as[r], b0);
                fma4(acc[1][r], as[r], b1);
            }
        }
        __syncthreads();
    }

    if (MODE == 0) {
        #pragma unroll
        for (int ch = 0; ch < 2; ++ch)
            #pragma unroll
            for (int rh = 0; rh < 2; ++rh)
                #pragma unroll
                for (int r = 0; r < 4; ++r) {
                    int gm = m0 + ra + rh*64 + r;
                    *(float4*)(cout + (size_t)gm*ldc + n0 + ca + ch*64) = acc[ch][rh*4+r];
                }
    } else {
        const int section = n0 >> 10;
        if (section == 2) {
            const int cb = n0 - 2048;
            #pragma unroll
            for (int ch = 0; ch < 2; ++ch)
                #pragma unroll
                for (int rh = 0; rh < 2; ++rh)
                    #pragma unroll
                    for (int r = 0; r < 4; ++r) {
                        int gm = m0 + ra + rh*64 + r;
                        *(float4*)(vbuf + (size_t)gm*1024 + cb + ca + ch*64) = acc[ch][rh*4+r];
                    }
        } else {
            float* wout = (section == 0) ? qwbuf : kwbuf;
            const int hbase = (n0 & 1023) >> 6;
            const int rr0 = (tid & 31) * 4;
            const int sg  = tid >> 5;
            #pragma unroll
            for (int hh = 0; hh < 2; ++hh) {
                __syncthreads();
                // dump this head's 128x64 C-half to LDS (stride 68)
                #pragma unroll
                for (int rh = 0; rh < 2; ++rh)
                    #pragma unroll
                    for (int r = 0; r < 4; ++r)
                        *(float4*)(lds + (ra + rh*64 + r)*68 + ca) = acc[hh][rh*4+r];
                __syncthreads();
                const int h = hbase + hh;
                float tnrm[4] = {0.f,0.f,0.f,0.f};
                #pragma unroll
                for (int i = 0; i < 16; ++i)
                    #pragma unroll
                    for (int r = 0; r < 4; ++r) {
                        float4 t4 = *(const float4*)(lds + (rr0+r)*68 + i*4);
                        tnrm[r] += dot4(t4, t4);
                    }
                #pragma unroll
                for (int ss = 0; ss < 2; ++ss) {
                    const int sp = sg*2 + ss;
                    const float* cp = centers + ((size_t)h*16 + sp)*64;
                    float s2  = __expf(2.0f * lscales[h*16+sp]);      // exp(ls)^2
                    float amp = 1.0f / (1.0f + __expf(-amps[h*16+sp]));
                    float cn = 0.f;
                    float cross[4] = {0.f,0.f,0.f,0.f};
                    #pragma unroll
                    for (int i = 0; i < 16; ++i) {
                        float4 c4 = *(const float4*)(cp + i*4);
                        cn += dot4(c4, c4);
                        #pragma unroll
                        for (int r = 0; r < 4; ++r) {
                            float4 t4 = *(const float4*)(lds + (rr0+r)*68 + i*4);
                            cross[r] += dot4(t4, c4);
                        }
                    }
                    #pragma unroll
                    for (int r = 0; r < 4; ++r) {
                        float dq = tnrm[r] - 2.f*cross[r] + cn;
                        float wv = __expf(-0.5f * dq / s2) * amp;
                        int gm = m0 + rr0 + r;
                        int bb = gm >> 11, sIdx = gm & (SEQ - 1);
                        wout[(((size_t)(bb*NH + h))*SEQ + sIdx)*16 + sp] = wv;
                    }
                }
            }
        }
    }
}

// ---------------------------------------------------------------------------
// K5: attention. Scores bounded in [0, ~8.6] -> no max-subtraction needed.
// Block: (bh, 64-query tile); loop 32-key tiles; scores->exp->LDS; PV in regs.
// ---------------------------------------------------------------------------
__global__ __launch_bounds__(256) void attn_kernel(
    const float* __restrict__ qw, const float* __restrict__ kw,
    const float* __restrict__ vbuf, float* __restrict__ ho)
{
    __shared__ float QWs[64*20];
    __shared__ float KWs[32*20];
    __shared__ float Vs[32*68];
    __shared__ float Es[32*68];
    const int tid = threadIdx.x;
    const int it = blockIdx.x;
    const int bh = blockIdx.y;
    const int b = bh >> 4;
    const int h = bh & 15;
    const int s0 = it * 64;
    {
        int row = tid >> 2, c4 = (tid & 3) * 4;
        *(float4*)(QWs + row*20 + c4) =
            *(const float4*)(qw + (((size_t)bh*SEQ) + s0 + row)*16 + c4);
    }
    const int rg = tid & 15;
    const int dg = tid >> 4;
    const int r0 = rg * 4;
    const int d0 = dg * 4;
    float4 accv[4];
    #pragma unroll
    for (int r = 0; r < 4; ++r) accv[r] = make_float4(0.f,0.f,0.f,0.f);
    float4 z = make_float4(0.f,0.f,0.f,0.f);

    for (int jt = 0; jt < SEQ/32; ++jt) {
        const int j0 = jt * 32;
        if (tid < 128) {
            int row = tid >> 2, c4 = (tid & 3) * 4;
            *(float4*)(KWs + row*20 + c4) =
                *(const float4*)(kw + (((size_t)bh*SEQ) + j0 + row)*16 + c4);
        }
        #pragma unroll
        for (int i = 0; i < 2; ++i) {
            int L = tid + i*256;
            int row = L >> 4, c4 = (L & 15) * 4;
            *(float4*)(Vs + row*68 + c4) =
                *(const float4*)(vbuf + ((size_t)(b*SEQ + j0 + row))*1024 + h*64 + c4);
        }
        __syncthreads();
        // scores: this thread does rows {rg+16r} x keys {2dg, 2dg+1}
        {
            const int jj0 = dg * 2;
            float4 k0[4], k1[4];
            #pragma unroll
            for (int i = 0; i < 4; ++i) {
                k0[i] = *(const float4*)(KWs + jj0*20 + i*4);
                k1[i] = *(const float4*)(KWs + (jj0+1)*20 + i*4);
            }
            #pragma unroll
            for (int r = 0; r < 4; ++r) {
                const int row = rg + 16*r;
                const float* qp = QWs + row*20;
                float4 q0 = *(const float4*)(qp);
                float4 q1 = *(const float4*)(qp+4);
                float4 q2 = *(const float4*)(qp+8);
                float4 q3 = *(const float4*)(qp+12);
                float sa = dot4(q0,k0[0]) + dot4(q1,k0[1]) + dot4(q2,k0[2]) + dot4(q3,k0[3]);
                float sb = dot4(q0,k1[0]) + dot4(q1,k1[1]) + dot4(q2,k1[2]) + dot4(q3,k1[3]);
                Es[jj0*68 + row]     = __expf(sa);
                Es[(jj0+1)*68 + row] = __expf(sb);
            }
        }
        __syncthreads();
        #pragma unroll 8
        for (int j = 0; j < 32; ++j) {
            float4 e4 = *(const float4*)(Es + j*68 + r0);
            float4 v4 = *(const float4*)(Vs + j*68 + d0);
            z.x += e4.x; z.y += e4.y; z.z += e4.z; z.w += e4.w;
            fma4(accv[0], e4.x, v4);
            fma4(accv[1], e4.y, v4);
            fma4(accv[2], e4.z, v4);
            fma4(accv[3], e4.w, v4);
        }
        __syncthreads();
    }
    float zz[4] = {z.x, z.y, z.z, z.w};
    #pragma unroll
    for (int r = 0; r < 4; ++r) {
        float inv = 1.0f / zz[r];            // z >= 2048 (all exp >= 1), safe
        float4 o = accv[r];
        o.x *= inv; o.y *= inv; o.z *= inv; o.w *= inv;
        *(float4*)(ho + ((size_t)(b*SEQ + s0 + r0 + r))*1024 + h*64 + d0) = o;
    }
}

// ---------------------------------------------------------------------------
extern "C" void kernel_launch(void* const* d_in, const int* in_sizes, int n_in,
                              void* d_out, int out_size, void* d_ws, size_t ws_size,
                              hipStream_t stream)
{
    const float* x       = (const float*)d_in[0];
    const float* qkv_w   = (const float*)d_in[1];
    const float* out_w   = (const float*)d_in[2];
    const float* centers = (const float*)d_in[3];
    const float* lscales = (const float*)d_in[4];
    const float* amps    = (const float*)d_in[5];
    float* out  = (float*)d_out;                      // [B,S,D]
    float* traj = out + (size_t)NB*SEQ*DIM;           // [B,S,D]

    float* w      = (float*)d_ws;
    float* vbuf   = w;                                //  4 Mi floats [B,S,D]
    float* ho     = w + 4194304;                      //  4 Mi floats [B,S,D]
    float* qwb    = w + 8388608;                      //  1 Mi floats [B,H,S,16]
    float* kwb    = qwb + 1048576;                    //  1 Mi
    float* sbuf   = kwb + 1048576;                    //  4096
    float* invbuf = sbuf + 4096;                      //  4096   (total ~42 MB)

    traj_stats_kernel<<<1024, 256, 0, stream>>>(x, sbuf, invbuf);
    traj_kernel<<<NB*SEQ, 256, 0, stream>>>(x, sbuf, invbuf, traj);
    gemm_kernel<1><<<dim3(24, 32), 256, 0, stream>>>(
        x, qkv_w, nullptr, 0, vbuf, qwb, kwb, centers, lscales, amps);
    attn_kernel<<<dim3(32, 32), 256, 0, stream>>>(qwb, kwb, vbuf, ho);
    gemm_kernel<0><<<dim3(8, 32), 256, 0, stream>>>(
        ho, out_w, out, 1024, nullptr, nullptr, nullptr, nullptr, nullptr, nullptr);
}

// Round 3
// 731.428 us; speedup vs baseline: 1.7637x; 1.7637x over previous
//
#include <hip/hip_runtime.h>
#include <math.h>

// Problem constants (B=2, S=2048, D=1024, H=16, hd=64, K=16)
#define SEQ 2048
#define DIM 1024
#define NB  2
#define NH  16

typedef __attribute__((ext_vector_type(8))) short short8;
typedef __attribute__((ext_vector_type(4))) float floatx4;

__device__ __forceinline__ float dot4(float4 a, float4 b) {
    return a.x*b.x + a.y*b.y + a.z*b.z + a.w*b.w;
}
__device__ __forceinline__ void fma4(float4& a, float s, float4 b) {
    a.x = fmaf(s, b.x, a.x); a.y = fmaf(s, b.y, a.y);
    a.z = fmaf(s, b.z, a.z); a.w = fmaf(s, b.w, a.w);
}
__device__ __forceinline__ ushort f2bf(float f) {
    unsigned u = __float_as_uint(f);
    return (ushort)((u + 0x7FFFu + ((u >> 16) & 1u)) >> 16);
}
__device__ __forceinline__ float bf2f(ushort h) {
    return __uint_as_float(((unsigned)h) << 16);
}
// async global->LDS, 16B per lane; LDS dest = wave-uniform base + lane*16
__device__ __forceinline__ void gload16(const void* g, char* lds_base) {
    __builtin_amdgcn_global_load_lds(
        (const __attribute__((address_space(1))) void*)g,
        (__attribute__((address_space(3))) void*)lds_base, 16, 0, 0);
}

// ---------------------------------------------------------------------------
// fp32 -> bf16 (hi only)
// ---------------------------------------------------------------------------
__global__ __launch_bounds__(256) void cvt_hi_kernel(
    const float* __restrict__ src, ushort* __restrict__ dst, int n)
{
    int i = (blockIdx.x * 256 + threadIdx.x) * 4;
    if (i >= n) return;
    float4 v = *(const float4*)(src + i);
    ushort4 o;
    o.x = f2bf(v.x); o.y = f2bf(v.y); o.z = f2bf(v.z); o.w = f2bf(v.w);
    *(ushort4*)(dst + i) = o;
}

// fp32 -> bf16 hi + lo (x ~= hi + lo, residual ~2^-17 relative)
__global__ __launch_bounds__(256) void cvt_split_kernel(
    const float* __restrict__ src, ushort* __restrict__ hi, ushort* __restrict__ lo, int n)
{
    int i = (blockIdx.x * 256 + threadIdx.x) * 4;
    if (i >= n) return;
    float4 v = *(const float4*)(src + i);
    ushort4 h, l;
    h.x = f2bf(v.x); l.x = f2bf(v.x - bf2f(h.x));
    h.y = f2bf(v.y); l.y = f2bf(v.y - bf2f(h.y));
    h.z = f2bf(v.z); l.z = f2bf(v.z - bf2f(h.z));
    h.w = f2bf(v.w); l.w = f2bf(v.w - bf2f(h.w));
    *(ushort4*)(hi + i) = h;
    *(ushort4*)(lo + i) = l;
}

// ---------------------------------------------------------------------------
// K1: per-diff stats: sbuf = tanh(|x[j+1]-x[j]|), invbuf = 1/max(|.|,1e-8)
// ---------------------------------------------------------------------------
__global__ __launch_bounds__(256) void traj_stats_kernel(
    const float* __restrict__ x, float* __restrict__ sbuf, float* __restrict__ invbuf)
{
    const int wave = threadIdx.x >> 6;
    const int lane = threadIdx.x & 63;
    const int row  = blockIdx.x * 4 + wave;
    const int NR = NB * (SEQ - 1);
    if (row >= NR) return;
    const int b = row / (SEQ - 1);
    const int j = row - b * (SEQ - 1);
    const float* x0 = x + ((size_t)(b * SEQ + j)) * DIM;
    const float* x1 = x0 + DIM;
    float sum = 0.f;
    #pragma unroll
    for (int q = 0; q < 4; ++q) {
        int idx = q * 256 + lane * 4;
        float4 a = *(const float4*)(x0 + idx);
        float4 c = *(const float4*)(x1 + idx);
        float dx = c.x-a.x, dy = c.y-a.y, dz = c.z-a.z, dw = c.w-a.w;
        sum += dx*dx + dy*dy + dz*dz + dw*dw;
    }
    #pragma unroll
    for (int off = 32; off > 0; off >>= 1) sum += __shfl_down(sum, off);
    if (lane == 0) {
        float mag = sqrtf(sum);
        sbuf[row]   = tanhf(mag);
        invbuf[row] = 1.0f / fmaxf(mag, 1e-8f);
    }
}

// ---------------------------------------------------------------------------
// K2: traj combine (window <= 8)
// ---------------------------------------------------------------------------
__global__ __launch_bounds__(256) void traj_kernel(
    const float* __restrict__ x, const float* __restrict__ sbuf,
    const float* __restrict__ invbuf, float* __restrict__ traj_out)
{
    const int bp = blockIdx.x;
    const int b  = bp >> 11;
    const int p  = bp & (SEQ - 1);
    int ws = p - 8; if (ws < 0) ws = 0;
    const int wlen = p - ws;
    const float wsz = (float)((p - ws) > 1 ? (p - ws) : 1);
    const int base = b * (SEQ - 1) + ws;

    float Z = 0.f;
    for (int t = 0; t < wlen; ++t)
        Z += sbuf[base + t] * ((float)(t + 1) / wsz);
    const float scale = 1.0f / fmaxf(Z, 1e-8f);

    const int d0 = threadIdx.x * 4;
    const float* xb = x + ((size_t)(b * SEQ + ws)) * DIM + d0;
    float4 prev = *(const float4*)xb;
    float4 acc = make_float4(0.f,0.f,0.f,0.f);
    for (int t = 0; t < wlen; ++t) {
        xb += DIM;
        float4 cur = *(const float4*)xb;
        float cc = sbuf[base + t] * ((float)(t + 1) / wsz) * invbuf[base + t] * scale;
        acc.x += cc * (cur.x - prev.x);
        acc.y += cc * (cur.y - prev.y);
        acc.z += cc * (cur.z - prev.z);
        acc.w += cc * (cur.w - prev.w);
        prev = cur;
    }
    *(float4*)(traj_out + (size_t)bp * DIM + d0) = acc;
}

// ---------------------------------------------------------------------------
// MFMA bf16 GEMM, m97 structure: C[M,N] = A[M,1024] @ B[N,1024]^T.
// 128x128 tile, BK=32, 4 waves 2x2, each wave 64x64 via 4x4 of 16x16x32.
// SPLIT=1: A ~= Ah+Al, B ~= Bh+Bl; C = Ah·Bh + Ah·Bl + Al·Bh (fp32-ish).
// EPI=0: fp32 store to cout (ldc). EPI=1 (q/k): fused splat-weight epilogue,
//        bf16 store to qwb (n0<1024) / kwb (else).
// ---------------------------------------------------------------------------
template<int SPLIT, int EPI>
__global__ __launch_bounds__(256) void mfma_gemm(
    const ushort* __restrict__ Ah, const ushort* __restrict__ Al,
    const ushort* __restrict__ Bh, const ushort* __restrict__ Bl,
    float* __restrict__ cout, int ldc,
    ushort* __restrict__ qwb, ushort* __restrict__ kwb,
    const float* __restrict__ centers, const float* __restrict__ lscales,
    const float* __restrict__ amps)
{
    constexpr int SMEM = EPI ? 34816 : (SPLIT ? 32768 : 16384);
    __shared__ char smem[SMEM];
    const int tid = threadIdx.x;
    const int l = tid & 63;
    const int w = tid >> 6;
    const int wm = w >> 1, wn = w & 1;
    const int n0 = blockIdx.x * 128;
    const int m0 = blockIdx.y * 128;

    char* a_h = smem;
    char* b_h = smem + 8192;
    char* a_l = smem + 16384;
    char* b_l = smem + 24576;

    // staging: wave w, inst i covers rows 32w+16i..+15 of the 128x32 tile
    const int srow = 32 * w + (l >> 2);
    const int scol = (l & 3) * 8;
    const ushort* Ahg = Ah + (size_t)(m0 + srow) * 1024 + scol;
    const ushort* Bhg = Bh + (size_t)(n0 + srow) * 1024 + scol;
    const ushort* Alg = SPLIT ? Al + (size_t)(m0 + srow) * 1024 + scol : nullptr;
    const ushort* Blg = SPLIT ? Bl + (size_t)(n0 + srow) * 1024 + scol : nullptr;

    floatx4 acc[4][4] = {};
    const int fr = l & 15;           // fragment row (m) / col (n)
    const int fq = (l >> 4) * 16;    // k-chunk byte offset (8 bf16)

    for (int kb = 0; kb < 1024; kb += 32) {
        if (kb) __syncthreads();
        gload16(Ahg + kb,             a_h + w*2048);
        gload16(Ahg + kb + 16*1024,   a_h + w*2048 + 1024);
        gload16(Bhg + kb,             b_h + w*2048);
        gload16(Bhg + kb + 16*1024,   b_h + w*2048 + 1024);
        if (SPLIT) {
            gload16(Alg + kb,           a_l + w*2048);
            gload16(Alg + kb + 16*1024, a_l + w*2048 + 1024);
            gload16(Blg + kb,           b_l + w*2048);
            gload16(Blg + kb + 16*1024, b_l + w*2048 + 1024);
        }
        __syncthreads();
        short8 fah[4], fbh[4], fal[4], fbl[4];
        #pragma unroll
        for (int t = 0; t < 4; ++t) {
            fah[t] = *(const short8*)(a_h + ((wm*64 + t*16 + fr) << 6) + fq);
            fbh[t] = *(const short8*)(b_h + ((wn*64 + t*16 + fr) << 6) + fq);
            if (SPLIT) {
                fal[t] = *(const short8*)(a_l + ((wm*64 + t*16 + fr) << 6) + fq);
                fbl[t] = *(const short8*)(b_l + ((wn*64 + t*16 + fr) << 6) + fq);
            }
        }
        #pragma unroll
        for (int it = 0; it < 4; ++it)
            #pragma unroll
            for (int jt = 0; jt < 4; ++jt) {
                acc[it][jt] = __builtin_amdgcn_mfma_f32_16x16x32_bf16(
                    fah[it], fbh[jt], acc[it][jt], 0, 0, 0);
                if (SPLIT) {
                    acc[it][jt] = __builtin_amdgcn_mfma_f32_16x16x32_bf16(
                        fah[it], fbl[jt], acc[it][jt], 0, 0, 0);
                    acc[it][jt] = __builtin_amdgcn_mfma_f32_16x16x32_bf16(
                        fal[it], fbh[jt], acc[it][jt], 0, 0, 0);
                }
            }
    }

    const int row0 = (l >> 4) * 4;   // C: row=(l>>4)*4+reg, col=l&15
    const int col  = l & 15;

    if (EPI == 0) {
        #pragma unroll
        for (int it = 0; it < 4; ++it)
            #pragma unroll
            for (int jt = 0; jt < 4; ++jt)
                #pragma unroll
                for (int r = 0; r < 4; ++r) {
                    int gm = m0 + wm*64 + it*16 + row0 + r;
                    int gn = n0 + wn*64 + jt*16 + col;
                    cout[(size_t)gm * ldc + gn] = acc[it][jt][r];
                }
    } else {
        // splat-weight epilogue: two heads per block (64 cols each)
        float* Cs = (float*)smem;                 // [128][68]
        ushort* wout = (n0 < 1024) ? qwb : kwb;
        const int hbase = (n0 & 1023) >> 6;
        const int rr0 = (tid & 31) * 4;
        const int sg  = tid >> 5;
        for (int hh = 0; hh < 2; ++hh) {
            __syncthreads();
            if (wn == hh) {
                #pragma unroll
                for (int it = 0; it < 4; ++it)
                    #pragma unroll
                    for (int jt = 0; jt < 4; ++jt)
                        #pragma unroll
                        for (int r = 0; r < 4; ++r)
                            Cs[(wm*64 + it*16 + row0 + r)*68 + jt*16 + col] = acc[it][jt][r];
            }
            __syncthreads();
            const int h = hbase + hh;
            float tnrm[4] = {0.f,0.f,0.f,0.f};
            #pragma unroll
            for (int i = 0; i < 16; ++i)
                #pragma unroll
                for (int r = 0; r < 4; ++r) {
                    float4 t4 = *(const float4*)(Cs + (rr0+r)*68 + i*4);
                    tnrm[r] += dot4(t4, t4);
                }
            #pragma unroll
            for (int ss = 0; ss < 2; ++ss) {
                const int sp = sg*2 + ss;
                const float* cp = centers + ((size_t)h*16 + sp)*64;
                float s2  = __expf(2.0f * lscales[h*16+sp]);
                float amp = 1.0f / (1.0f + __expf(-amps[h*16+sp]));
                float cn = 0.f;
                float cross[4] = {0.f,0.f,0.f,0.f};
                #pragma unroll
                for (int i = 0; i < 16; ++i) {
                    float4 c4 = *(const float4*)(cp + i*4);
                    cn += dot4(c4, c4);
                    #pragma unroll
                    for (int r = 0; r < 4; ++r) {
                        float4 t4 = *(const float4*)(Cs + (rr0+r)*68 + i*4);
                        cross[r] += dot4(t4, c4);
                    }
                }
                #pragma unroll
                for (int r = 0; r < 4; ++r) {
                    float dq = tnrm[r] - 2.f*cross[r] + cn;
                    float wv = __expf(-0.5f * dq / s2) * amp;
                    int gm = m0 + rr0 + r;
                    int bb = gm >> 11, sIdx = gm & (SEQ - 1);
                    wout[(((size_t)(bb*NH + h))*SEQ + sIdx)*16 + sp] = f2bf(wv);
                }
            }
        }
    }
}

// ---------------------------------------------------------------------------
// Attention: scores in [0, ~1e-10] -> exp ~= 1; no max-subtract needed.
// qw/kw bf16 [B,H,S,16]; v fp32 [B,S,D]; output ho written as bf16 hi/lo.
// ---------------------------------------------------------------------------
__global__ __launch_bounds__(256) void attn_kernel(
    const ushort* __restrict__ qw, const ushort* __restrict__ kw,
    const float* __restrict__ vbf, ushort* __restrict__ hoh, ushort* __restrict__ hol)
{
    __shared__ float QWs[64*20];
    __shared__ float KWs[32*20];
    __shared__ float Vs[32*68];
    __shared__ float Es[32*68];
    const int tid = threadIdx.x;
    const int it = blockIdx.x;
    const int bh = blockIdx.y;
    const int b = bh >> 4;
    const int h = bh & 15;
    const int s0 = it * 64;
    {
        int row = tid >> 2, c4 = (tid & 3) * 4;
        ushort4 uv = *(const ushort4*)(qw + (((size_t)bh*SEQ) + s0 + row)*16 + c4);
        QWs[row*20+c4+0] = bf2f(uv.x); QWs[row*20+c4+1] = bf2f(uv.y);
        QWs[row*20+c4+2] = bf2f(uv.z); QWs[row*20+c4+3] = bf2f(uv.w);
    }
    const int rg = tid & 15;
    const int dg = tid >> 4;
    const int r0 = rg * 4;
    const int d0 = dg * 4;
    float4 accv[4];
    #pragma unroll
    for (int r = 0; r < 4; ++r) accv[r] = make_float4(0.f,0.f,0.f,0.f);
    float4 z = make_float4(0.f,0.f,0.f,0.f);

    for (int jt2 = 0; jt2 < SEQ/32; ++jt2) {
        const int j0 = jt2 * 32;
        if (tid < 128) {
            int row = tid >> 2, c4 = (tid & 3) * 4;
            ushort4 uv = *(const ushort4*)(kw + (((size_t)bh*SEQ) + j0 + row)*16 + c4);
            KWs[row*20+c4+0] = bf2f(uv.x); KWs[row*20+c4+1] = bf2f(uv.y);
            KWs[row*20+c4+2] = bf2f(uv.z); KWs[row*20+c4+3] = bf2f(uv.w);
        }
        #pragma unroll
        for (int i = 0; i < 2; ++i) {
            int L = tid + i*256;
            int row = L >> 4, c4 = (L & 15) * 4;
            *(float4*)(Vs + row*68 + c4) =
                *(const float4*)(vbf + ((size_t)(b*SEQ + j0 + row))*1024 + h*64 + c4);
        }
        __syncthreads();
        {
            const int jj0 = dg * 2;
            float4 k0[4], k1[4];
            #pragma unroll
            for (int i = 0; i < 4; ++i) {
                k0[i] = *(const float4*)(KWs + jj0*20 + i*4);
                k1[i] = *(const float4*)(KWs + (jj0+1)*20 + i*4);
            }
            #pragma unroll
            for (int r = 0; r < 4; ++r) {
                const int row = rg + 16*r;
                const float* qp = QWs + row*20;
                float4 q0 = *(const float4*)(qp);
                float4 q1 = *(const float4*)(qp+4);
                float4 q2 = *(const float4*)(qp+8);
                float4 q3 = *(const float4*)(qp+12);
                float sa = dot4(q0,k0[0]) + dot4(q1,k0[1]) + dot4(q2,k0[2]) + dot4(q3,k0[3]);
                float sb = dot4(q0,k1[0]) + dot4(q1,k1[1]) + dot4(q2,k1[2]) + dot4(q3,k1[3]);
                Es[jj0*68 + row]     = __expf(sa);
                Es[(jj0+1)*68 + row] = __expf(sb);
            }
        }
        __syncthreads();
        #pragma unroll 8
        for (int j = 0; j < 32; ++j) {
            float4 e4 = *(const float4*)(Es + j*68 + r0);
            float4 v4 = *(const float4*)(Vs + j*68 + d0);
            z.x += e4.x; z.y += e4.y; z.z += e4.z; z.w += e4.w;
            fma4(accv[0], e4.x, v4);
            fma4(accv[1], e4.y, v4);
            fma4(accv[2], e4.z, v4);
            fma4(accv[3], e4.w, v4);
        }
        __syncthreads();
    }
    float zz[4] = {z.x, z.y, z.z, z.w};
    #pragma unroll
    for (int r = 0; r < 4; ++r) {
        float inv = 1.0f / zz[r];
        float4 o = accv[r];
        o.x *= inv; o.y *= inv; o.z *= inv; o.w *= inv;
        ushort4 h4, l4;
        h4.x = f2bf(o.x); l4.x = f2bf(o.x - bf2f(h4.x));
        h4.y = f2bf(o.y); l4.y = f2bf(o.y - bf2f(h4.y));
        h4.z = f2bf(o.z); l4.z = f2bf(o.z - bf2f(h4.z));
        h4.w = f2bf(o.w); l4.w = f2bf(o.w - bf2f(h4.w));
        size_t idx = ((size_t)(b*SEQ + s0 + r0 + r))*1024 + h*64 + d0;
        *(ushort4*)(hoh + idx) = h4;
        *(ushort4*)(hol + idx) = l4;
    }
}

// ---------------------------------------------------------------------------
extern "C" void kernel_launch(void* const* d_in, const int* in_sizes, int n_in,
                              void* d_out, int out_size, void* d_ws, size_t ws_size,
                              hipStream_t stream)
{
    const float* x       = (const float*)d_in[0];
    const float* qkv_w   = (const float*)d_in[1];
    const float* out_w   = (const float*)d_in[2];
    const float* centers = (const float*)d_in[3];
    const float* lscales = (const float*)d_in[4];
    const float* amps    = (const float*)d_in[5];
    float* out  = (float*)d_out;                      // [B,S,D]
    float* traj = out + (size_t)NB*SEQ*DIM;           // [B,S,D]

    char* wsb = (char*)d_ws;                          // 40.03 MB total
    ushort* xh   = (ushort*)(wsb);                    // [0,8) MB  bf16 x hi
    ushort* xl   = (ushort*)(wsb + (8u<<20));         // [8,16) MB bf16 x lo
    ushort* wh   = (ushort*)(wsb + (16u<<20));        // [16,22) MB qkv_w hi (3072x1024)
    ushort* wlv  = (ushort*)(wsb + (22u<<20));        // [22,24) MB v-weight lo (1024x1024)
    float*  vbf  = (float*)(wsb + (24u<<20));         // [24,40) MB v fp32 [B,S,D]
    float*  sbuf = (float*)(wsb + (40u<<20));         // 16 KB
    float*  invb = sbuf + 4096;                       // 16 KB
    // aliases (regions dead by the time they're written):
    ushort* qwbh = wlv;                               // after v_gemm
    ushort* kwbh = wh + 2048*1024;                    // wh bytes [4,6) MB, after v_gemm
    ushort* owh  = wh;                                // wh bytes [0,2) MB, after qk_gemm
    ushort* owl  = wh + 1048576;                      // wh bytes [2,4) MB
    ushort* hoh  = xh;                                // after qk_gemm
    ushort* hol  = xl;

    cvt_split_kernel<<<4096, 256, 0, stream>>>(x, xh, xl, 4194304);
    cvt_hi_kernel<<<3072, 256, 0, stream>>>(qkv_w, wh, 3145728);
    cvt_split_kernel<<<1024, 256, 0, stream>>>(qkv_w + 2097152, wh + 2097152, wlv, 1048576);
    traj_stats_kernel<<<1024, 256, 0, stream>>>(x, sbuf, invb);
    traj_kernel<<<NB*SEQ, 256, 0, stream>>>(x, sbuf, invb, traj);
    // v = x @ Wv^T  (split, fp32 out)
    mfma_gemm<1,0><<<dim3(8, 32), 256, 0, stream>>>(
        xh, xl, wh + 2048*1024, wlv, vbf, 1024,
        nullptr, nullptr, nullptr, nullptr, nullptr);
    // q,k weights (plain bf16) with fused splat epilogue
    mfma_gemm<0,1><<<dim3(16, 32), 256, 0, stream>>>(
        xh, nullptr, wh, nullptr, nullptr, 0,
        qwbh, kwbh, centers, lscales, amps);
    cvt_split_kernel<<<1024, 256, 0, stream>>>(out_w, owh, owl, 1048576);
    attn_kernel<<<dim3(32, 32), 256, 0, stream>>>(qwbh, kwbh, vbf, hoh, hol);
    // out = ho @ out_w^T  (split, fp32 out)
    mfma_gemm<1,0><<<dim3(8, 32), 256, 0, stream>>>(
        hoh, hol, owh, owl, out, 1024,
        nullptr, nullptr, nullptr, nullptr, nullptr);
}

// Round 4
// 448.349 us; speedup vs baseline: 2.8773x; 1.6314x over previous
//
#include <hip/hip_runtime.h>
#include <math.h>

// Problem constants (B=2, S=2048, D=1024, H=16, hd=64, K=16)
#define SEQ 2048
#define DIM 1024
#define NB  2
#define NH  16

typedef __attribute__((ext_vector_type(8))) short short8;
typedef __attribute__((ext_vector_type(4))) float floatx4;

__device__ __forceinline__ float dot4(float4 a, float4 b) {
    return a.x*b.x + a.y*b.y + a.z*b.z + a.w*b.w;
}
__device__ __forceinline__ ushort f2bf(float f) {
    unsigned u = __float_as_uint(f);
    return (ushort)((u + 0x7FFFu + ((u >> 16) & 1u)) >> 16);
}
__device__ __forceinline__ float bf2f(ushort h) {
    return __uint_as_float(((unsigned)h) << 16);
}
// async global->LDS, 16B per lane; LDS dest = wave-uniform base + lane*16
__device__ __forceinline__ void gload16(const void* g, char* lds_base) {
    __builtin_amdgcn_global_load_lds(
        (const __attribute__((address_space(1))) void*)g,
        (__attribute__((address_space(3))) void*)lds_base, 16, 0, 0);
}

// ---------------------------------------------------------------------------
// fp32 -> bf16 (hi only)
// ---------------------------------------------------------------------------
__global__ __launch_bounds__(256) void cvt_hi_kernel(
    const float* __restrict__ src, ushort* __restrict__ dst, int n)
{
    int i = (blockIdx.x * 256 + threadIdx.x) * 4;
    if (i >= n) return;
    float4 v = *(const float4*)(src + i);
    ushort4 o;
    o.x = f2bf(v.x); o.y = f2bf(v.y); o.z = f2bf(v.z); o.w = f2bf(v.w);
    *(ushort4*)(dst + i) = o;
}

// fp32 -> bf16 hi + lo (x ~= hi + lo, residual ~2^-17 relative)
__global__ __launch_bounds__(256) void cvt_split_kernel(
    const float* __restrict__ src, ushort* __restrict__ hi, ushort* __restrict__ lo, int n)
{
    int i = (blockIdx.x * 256 + threadIdx.x) * 4;
    if (i >= n) return;
    float4 v = *(const float4*)(src + i);
    ushort4 h, l;
    h.x = f2bf(v.x); l.x = f2bf(v.x - bf2f(h.x));
    h.y = f2bf(v.y); l.y = f2bf(v.y - bf2f(h.y));
    h.z = f2bf(v.z); l.z = f2bf(v.z - bf2f(h.z));
    h.w = f2bf(v.w); l.w = f2bf(v.w - bf2f(h.w));
    *(ushort4*)(hi + i) = h;
    *(ushort4*)(lo + i) = l;
}

// ---------------------------------------------------------------------------
// K1: per-diff stats
// ---------------------------------------------------------------------------
__global__ __launch_bounds__(256) void traj_stats_kernel(
    const float* __restrict__ x, float* __restrict__ sbuf, float* __restrict__ invbuf)
{
    const int wave = threadIdx.x >> 6;
    const int lane = threadIdx.x & 63;
    const int row  = blockIdx.x * 4 + wave;
    const int NR = NB * (SEQ - 1);
    if (row >= NR) return;
    const int b = row / (SEQ - 1);
    const int j = row - b * (SEQ - 1);
    const float* x0 = x + ((size_t)(b * SEQ + j)) * DIM;
    const float* x1 = x0 + DIM;
    float sum = 0.f;
    #pragma unroll
    for (int q = 0; q < 4; ++q) {
        int idx = q * 256 + lane * 4;
        float4 a = *(const float4*)(x0 + idx);
        float4 c = *(const float4*)(x1 + idx);
        float dx = c.x-a.x, dy = c.y-a.y, dz = c.z-a.z, dw = c.w-a.w;
        sum += dx*dx + dy*dy + dz*dz + dw*dw;
    }
    #pragma unroll
    for (int off = 32; off > 0; off >>= 1) sum += __shfl_down(sum, off);
    if (lane == 0) {
        float mag = sqrtf(sum);
        sbuf[row]   = tanhf(mag);
        invbuf[row] = 1.0f / fmaxf(mag, 1e-8f);
    }
}

// ---------------------------------------------------------------------------
// K2: traj combine (window <= 8)
// ---------------------------------------------------------------------------
__global__ __launch_bounds__(256) void traj_kernel(
    const float* __restrict__ x, const float* __restrict__ sbuf,
    const float* __restrict__ invbuf, float* __restrict__ traj_out)
{
    const int bp = blockIdx.x;
    const int b  = bp >> 11;
    const int p  = bp & (SEQ - 1);
    int ws = p - 8; if (ws < 0) ws = 0;
    const int wlen = p - ws;
    const float wsz = (float)((p - ws) > 1 ? (p - ws) : 1);
    const int base = b * (SEQ - 1) + ws;

    float Z = 0.f;
    for (int t = 0; t < wlen; ++t)
        Z += sbuf[base + t] * ((float)(t + 1) / wsz);
    const float scale = 1.0f / fmaxf(Z, 1e-8f);

    const int d0 = threadIdx.x * 4;
    const float* xb = x + ((size_t)(b * SEQ + ws)) * DIM + d0;
    float4 prev = *(const float4*)xb;
    float4 acc = make_float4(0.f,0.f,0.f,0.f);
    for (int t = 0; t < wlen; ++t) {
        xb += DIM;
        float4 cur = *(const float4*)xb;
        float cc = sbuf[base + t] * ((float)(t + 1) / wsz) * invbuf[base + t] * scale;
        acc.x += cc * (cur.x - prev.x);
        acc.y += cc * (cur.y - prev.y);
        acc.z += cc * (cur.z - prev.z);
        acc.w += cc * (cur.w - prev.w);
        prev = cur;
    }
    *(float4*)(traj_out + (size_t)bp * DIM + d0) = acc;
}

// ---------------------------------------------------------------------------
// MFMA bf16 GEMM, m97 structure: C[M,N] = A[M,1024] @ B[N,1024]^T.
// 128x128 tile, BK=32, 4 waves 2x2, each wave 64x64 via 4x4 of 16x16x32.
// SPLIT=1: A ~= Ah+Al, B ~= Bh+Bl; C = Ah·Bh + Ah·Bl + Al·Bh (fp32-ish).
// EPI=0: fp32 store to cout (ldc).
// EPI=1 (q/k): fused splat-weight epilogue, bf16 -> qwb (n0<1024) / kwb.
// EPI=2 (v^T): bf16 store to vbt[b][m][token&2047] (qwb = vbt), M=1024 rows.
// ---------------------------------------------------------------------------
template<int SPLIT, int EPI>
__global__ __launch_bounds__(256) void mfma_gemm(
    const ushort* __restrict__ Ah, const ushort* __restrict__ Al,
    const ushort* __restrict__ Bh, const ushort* __restrict__ Bl,
    float* __restrict__ cout, int ldc,
    ushort* __restrict__ qwb, ushort* __restrict__ kwb,
    const float* __restrict__ centers, const float* __restrict__ lscales,
    const float* __restrict__ amps)
{
    constexpr int SMEM = (EPI == 1) ? 34816 : (SPLIT ? 32768 : 16384);
    __shared__ char smem[SMEM];
    const int tid = threadIdx.x;
    const int l = tid & 63;
    const int w = tid >> 6;
    const int wm = w >> 1, wn = w & 1;
    const int n0 = blockIdx.x * 128;
    const int m0 = blockIdx.y * 128;

    char* a_h = smem;
    char* b_h = smem + 8192;
    char* a_l = smem + 16384;
    char* b_l = smem + 24576;

    const int srow = 32 * w + (l >> 2);
    const int scol = (l & 3) * 8;
    const ushort* Ahg = Ah + (size_t)(m0 + srow) * 1024 + scol;
    const ushort* Bhg = Bh + (size_t)(n0 + srow) * 1024 + scol;
    const ushort* Alg = SPLIT ? Al + (size_t)(m0 + srow) * 1024 + scol : nullptr;
    const ushort* Blg = SPLIT ? Bl + (size_t)(n0 + srow) * 1024 + scol : nullptr;

    floatx4 acc[4][4] = {};
    const int fr = l & 15;
    const int fq = (l >> 4) * 16;

    for (int kb = 0; kb < 1024; kb += 32) {
        if (kb) __syncthreads();
        gload16(Ahg + kb,             a_h + w*2048);
        gload16(Ahg + kb + 16*1024,   a_h + w*2048 + 1024);
        gload16(Bhg + kb,             b_h + w*2048);
        gload16(Bhg + kb + 16*1024,   b_h + w*2048 + 1024);
        if (SPLIT) {
            gload16(Alg + kb,           a_l + w*2048);
            gload16(Alg + kb + 16*1024, a_l + w*2048 + 1024);
            gload16(Blg + kb,           b_l + w*2048);
            gload16(Blg + kb + 16*1024, b_l + w*2048 + 1024);
        }
        __syncthreads();
        short8 fah[4], fbh[4], fal[4], fbl[4];
        #pragma unroll
        for (int t = 0; t < 4; ++t) {
            fah[t] = *(const short8*)(a_h + ((wm*64 + t*16 + fr) << 6) + fq);
            fbh[t] = *(const short8*)(b_h + ((wn*64 + t*16 + fr) << 6) + fq);
            if (SPLIT) {
                fal[t] = *(const short8*)(a_l + ((wm*64 + t*16 + fr) << 6) + fq);
                fbl[t] = *(const short8*)(b_l + ((wn*64 + t*16 + fr) << 6) + fq);
            }
        }
        #pragma unroll
        for (int it = 0; it < 4; ++it)
            #pragma unroll
            for (int jt = 0; jt < 4; ++jt) {
                acc[it][jt] = __builtin_amdgcn_mfma_f32_16x16x32_bf16(
                    fah[it], fbh[jt], acc[it][jt], 0, 0, 0);
                if (SPLIT) {
                    acc[it][jt] = __builtin_amdgcn_mfma_f32_16x16x32_bf16(
                        fah[it], fbl[jt], acc[it][jt], 0, 0, 0);
                    acc[it][jt] = __builtin_amdgcn_mfma_f32_16x16x32_bf16(
                        fal[it], fbh[jt], acc[it][jt], 0, 0, 0);
                }
            }
    }

    const int row0 = (l >> 4) * 4;   // C: row=(l>>4)*4+reg, col=l&15
    const int col  = l & 15;

    if (EPI == 0) {
        #pragma unroll
        for (int it = 0; it < 4; ++it)
            #pragma unroll
            for (int jt = 0; jt < 4; ++jt)
                #pragma unroll
                for (int r = 0; r < 4; ++r) {
                    int gm = m0 + wm*64 + it*16 + row0 + r;
                    int gn = n0 + wn*64 + jt*16 + col;
                    cout[(size_t)gm * ldc + gn] = acc[it][jt][r];
                }
    } else if (EPI == 2) {
        // transposed v store: rows m = h*64+d, cols n = token
        #pragma unroll
        for (int it = 0; it < 4; ++it)
            #pragma unroll
            for (int jt = 0; jt < 4; ++jt)
                #pragma unroll
                for (int r = 0; r < 4; ++r) {
                    int md = m0 + wm*64 + it*16 + row0 + r;
                    int t  = n0 + wn*64 + jt*16 + col;
                    int bb = t >> 11, ss = t & (SEQ - 1);
                    qwb[((size_t)bb << 21) + (size_t)md * SEQ + ss] = f2bf(acc[it][jt][r]);
                }
    } else {
        // splat-weight epilogue: two heads per block (64 cols each)
        float* Cs = (float*)smem;                 // [128][68]
        ushort* wout = (n0 < 1024) ? qwb : kwb;
        const int hbase = (n0 & 1023) >> 6;
        const int rr0 = (tid & 31) * 4;
        const int sg  = tid >> 5;
        for (int hh = 0; hh < 2; ++hh) {
            __syncthreads();
            if (wn == hh) {
                #pragma unroll
                for (int it = 0; it < 4; ++it)
                    #pragma unroll
                    for (int jt = 0; jt < 4; ++jt)
                        #pragma unroll
                        for (int r = 0; r < 4; ++r)
                            Cs[(wm*64 + it*16 + row0 + r)*68 + jt*16 + col] = acc[it][jt][r];
            }
            __syncthreads();
            const int h = hbase + hh;
            float tnrm[4] = {0.f,0.f,0.f,0.f};
            #pragma unroll
            for (int i = 0; i < 16; ++i)
                #pragma unroll
                for (int r = 0; r < 4; ++r) {
                    float4 t4 = *(const float4*)(Cs + (rr0+r)*68 + i*4);
                    tnrm[r] += dot4(t4, t4);
                }
            #pragma unroll
            for (int ss = 0; ss < 2; ++ss) {
                const int sp = sg*2 + ss;
                const float* cp = centers + ((size_t)h*16 + sp)*64;
                float s2  = __expf(2.0f * lscales[h*16+sp]);
                float amp = 1.0f / (1.0f + __expf(-amps[h*16+sp]));
                float cn = 0.f;
                float cross[4] = {0.f,0.f,0.f,0.f};
                #pragma unroll
                for (int i = 0; i < 16; ++i) {
                    float4 c4 = *(const float4*)(cp + i*4);
                    cn += dot4(c4, c4);
                    #pragma unroll
                    for (int r = 0; r < 4; ++r) {
                        float4 t4 = *(const float4*)(Cs + (rr0+r)*68 + i*4);
                        cross[r] += dot4(t4, c4);
                    }
                }
                #pragma unroll
                for (int r = 0; r < 4; ++r) {
                    float dq = tnrm[r] - 2.f*cross[r] + cn;
                    float wv = __expf(-0.5f * dq / s2) * amp;
                    int gm = m0 + rr0 + r;
                    int bb = gm >> 11, sIdx = gm & (SEQ - 1);
                    wout[(((size_t)(bb*NH + h))*SEQ + sIdx)*16 + sp] = f2bf(wv);
                }
            }
        }
    }
}

// ---------------------------------------------------------------------------
// MFMA flash attention. Scores >= 0 and <= ~4e-4 -> no max-subtract.
// qw/kw bf16 [B,H,S,16]; V^T bf16 [B,H,64,S]; out hi/lo bf16 [B,S,D].
// Block: 4 waves; wave w = 16 queries; key chunks of 64.
// Score: 16x16x32 mfma, k=16 real + 16 zero (lanes>=32 carry zero frags).
// PV: 16x16x32, V^T/P staged with XOR-swizzled 16B blocks (conflict-free).
// z via ones-B mfma (same C rows as O -> lane-local divide).
// ---------------------------------------------------------------------------
__global__ __launch_bounds__(256) void attn_kernel(
    const ushort* __restrict__ qw, const ushort* __restrict__ kw,
    const ushort* __restrict__ vbt, ushort* __restrict__ hoh, ushort* __restrict__ hol)
{
    __shared__ ushort KWs[64*16];        // 2 KB  [key][16]
    __shared__ ushort VTs[64*64];        // 8 KB  [d][key blocks, xor-swizzled]
    __shared__ ushort Ps[4][16*64];      // 8 KB  per-wave P [q][key blocks, xor-swizzled]
    const int tid = threadIdx.x;
    const int l = tid & 63;
    const int w = tid >> 6;
    const int bh = blockIdx.y;
    const int b = bh >> 4;
    const int h = bh & 15;
    const int s0 = blockIdx.x * 64;
    const int qrow = l & 15;
    const int quad = l >> 4;

    // persistent QW A-frag: m=q (l&15), k = quad*8+j (quads 0,1 real; 2,3 zero)
    short8 aq = {};
    if (l < 32)
        aq = *(const short8*)(qw + (((size_t)bh*SEQ) + s0 + w*16 + qrow)*16 + quad*8);

    const ushort* kwb = kw + ((size_t)bh*SEQ)*16;
    const ushort* vtb = vbt + ((size_t)(b*1024 + h*64))*SEQ;

    floatx4 accv[4] = {};
    floatx4 accz = {};
    floatx4 zero = {};
    short8 ones;
    #pragma unroll
    for (int i = 0; i < 8; ++i) ones[i] = (short)0x3F80;

    // staging addresses (per chunk j0): KW by waves 0,1; VT 2 insts/wave
    const int vd0 = w*2*8 + (l >> 3);        // inst w*2 row
    const int vkb0 = (l & 7) ^ (vd0 & 7);
    const int vd1 = (w*2+1)*8 + (l >> 3);
    const int vkb1 = (l & 7) ^ (vd1 & 7);

    for (int jt = 0; jt < SEQ/64; ++jt) {
        const int j0 = jt * 64;
        if (jt) __syncthreads();
        if (w < 2)
            gload16(kwb + (size_t)(j0 + w*32)*16 + l*8, (char*)KWs + w*1024);
        gload16(vtb + (size_t)vd0*SEQ + j0 + vkb0*8, (char*)VTs + (w*2  )*1024);
        gload16(vtb + (size_t)vd1*SEQ + j0 + vkb1*8, (char*)VTs + (w*2+1)*1024);
        __syncthreads();

        // scores: 4 key-tiles of 16
        floatx4 sc[4];
        #pragma unroll
        for (int kt = 0; kt < 4; ++kt) {
            short8 bk = {};
            if (l < 32)
                bk = *(const short8*)(KWs + (kt*16 + qrow)*16 + quad*8);
            sc[kt] = __builtin_amdgcn_mfma_f32_16x16x32_bf16(aq, bk, zero, 0, 0, 0);
        }
        // exp -> bf16(trunc) -> P LDS (xor-swizzled 16B blocks)
        ushort* Pw = Ps[w];
        #pragma unroll
        for (int kt = 0; kt < 4; ++kt)
            #pragma unroll
            for (int r = 0; r < 4; ++r) {
                float e = __expf(sc[kt][r]);
                int q = quad*4 + r;
                int key = kt*16 + qrow;
                Pw[q*64 + ((((key>>3) ^ (q&7)) << 3) | (key & 7))] =
                    (ushort)(__float_as_uint(e) >> 16);
            }
        // PV + z: 2 k-chunks of 32
        #pragma unroll
        for (int kc = 0; kc < 2; ++kc) {
            int kb = kc*4 + quad;
            short8 pa = *(const short8*)(Pw + qrow*64 + ((kb ^ (qrow & 7)) << 3));
            #pragma unroll
            for (int nt = 0; nt < 4; ++nt) {
                int d = nt*16 + qrow;
                short8 vb8 = *(const short8*)(VTs + d*64 + ((kb ^ (d & 7)) << 3));
                accv[nt] = __builtin_amdgcn_mfma_f32_16x16x32_bf16(pa, vb8, accv[nt], 0, 0, 0);
            }
            accz = __builtin_amdgcn_mfma_f32_16x16x32_bf16(pa, ones, accz, 0, 0, 0);
        }
    }

    // epilogue: divide by z (same C rows), hi/lo split store
    #pragma unroll
    for (int r = 0; r < 4; ++r) {
        float inv = 1.0f / accz[r];
        int s = s0 + w*16 + quad*4 + r;
        size_t base = ((size_t)(b*SEQ + s))*1024 + h*64;
        #pragma unroll
        for (int nt = 0; nt < 4; ++nt) {
            float val = accv[nt][r] * inv;
            ushort hi = f2bf(val);
            ushort lo = f2bf(val - bf2f(hi));
            hoh[base + nt*16 + qrow] = hi;
            hol[base + nt*16 + qrow] = lo;
        }
    }
}

// ---------------------------------------------------------------------------
extern "C" void kernel_launch(void* const* d_in, const int* in_sizes, int n_in,
                              void* d_out, int out_size, void* d_ws, size_t ws_size,
                              hipStream_t stream)
{
    const float* x       = (const float*)d_in[0];
    const float* qkv_w   = (const float*)d_in[1];
    const float* out_w   = (const float*)d_in[2];
    const float* centers = (const float*)d_in[3];
    const float* lscales = (const float*)d_in[4];
    const float* amps    = (const float*)d_in[5];
    float* out  = (float*)d_out;                      // [B,S,D]
    float* traj = out + (size_t)NB*SEQ*DIM;           // [B,S,D]

    char* wsb = (char*)d_ws;                          // 40.03 MB total
    ushort* xh   = (ushort*)(wsb);                    // [0,8) MB  bf16 x hi
    ushort* xl   = (ushort*)(wsb + (8u<<20));         // [8,16) MB bf16 x lo
    ushort* wh   = (ushort*)(wsb + (16u<<20));        // [16,22) MB qkv_w hi (3072x1024)
    ushort* wlv  = (ushort*)(wsb + (22u<<20));        // [22,24) MB v-weight lo (1024x1024)
    ushort* vbt  = (ushort*)(wsb + (24u<<20));        // [24,32) MB v^T bf16 [B,H,64,S]
    float*  sbuf = (float*)(wsb + (40u<<20));         // 16 KB
    float*  invb = sbuf + 4096;                       // 16 KB
    // aliases (regions dead by the time they're written):
    ushort* qwbh = wlv;                               // after v_gemm
    ushort* kwbh = wh + 2048*1024;                    // wh [4,6) MB, after v_gemm
    ushort* owh  = wh;                                // wh [0,2) MB, after qk_gemm
    ushort* owl  = wh + 1048576;                      // wh [2,4) MB
    ushort* hoh  = xh;                                // after qk_gemm + v_gemm
    ushort* hol  = xl;

    cvt_split_kernel<<<4096, 256, 0, stream>>>(x, xh, xl, 4194304);
    cvt_hi_kernel<<<3072, 256, 0, stream>>>(qkv_w, wh, 3145728);
    cvt_split_kernel<<<1024, 256, 0, stream>>>(qkv_w + 2097152, wh + 2097152, wlv, 1048576);
    traj_stats_kernel<<<1024, 256, 0, stream>>>(x, sbuf, invb);
    traj_kernel<<<NB*SEQ, 256, 0, stream>>>(x, sbuf, invb, traj);
    // v^T = Wv @ x^T  (split, bf16 transposed store [B,H,64,S])
    mfma_gemm<1,2><<<dim3(32, 8), 256, 0, stream>>>(
        wh + 2048*1024, wlv, xh, xl, nullptr, 0,
        vbt, nullptr, nullptr, nullptr, nullptr);
    // q,k weights (plain bf16) with fused splat epilogue
    mfma_gemm<0,1><<<dim3(16, 32), 256, 0, stream>>>(
        xh, nullptr, wh, nullptr, nullptr, 0,
        qwbh, kwbh, centers, lscales, amps);
    cvt_split_kernel<<<1024, 256, 0, stream>>>(out_w, owh, owl, 1048576);
    attn_kernel<<<dim3(32, 32), 256, 0, stream>>>(qwbh, kwbh, vbt, hoh, hol);
    // out = ho @ out_w^T  (split, fp32 out)
    mfma_gemm<1,0><<<dim3(8, 32), 256, 0, stream>>>(
        hoh, hol, owh, owl, out, 1024,
        nullptr, nullptr, nullptr, nullptr, nullptr);
}

// Round 5
// 304.168 us; speedup vs baseline: 4.2412x; 1.4740x over previous
//
#include <hip/hip_runtime.h>
#include <math.h>

// Problem constants (B=2, S=2048, D=1024, H=16, hd=64, K=16)
#define SEQ 2048
#define DIM 1024
#define NB  2
#define NH  16

typedef __attribute__((ext_vector_type(8))) short short8;
typedef __attribute__((ext_vector_type(4))) float floatx4;

__device__ __forceinline__ ushort f2bf(float f) {
    unsigned u = __float_as_uint(f);
    return (ushort)((u + 0x7FFFu + ((u >> 16) & 1u)) >> 16);
}
__device__ __forceinline__ float bf2f(ushort h) {
    return __uint_as_float(((unsigned)h) << 16);
}
// async global->LDS, 16B per lane; LDS dest = wave-uniform base + lane*16
__device__ __forceinline__ void gload16(const void* g, char* lds_base) {
    __builtin_amdgcn_global_load_lds(
        (const __attribute__((address_space(1))) void*)g,
        (__attribute__((address_space(3))) void*)lds_base, 16, 0, 0);
}

// ---------------------------------------------------------------------------
// fp32 -> bf16 (hi only)
// ---------------------------------------------------------------------------
__global__ __launch_bounds__(256) void cvt_hi_kernel(
    const float* __restrict__ src, ushort* __restrict__ dst, int n)
{
    int i = (blockIdx.x * 256 + threadIdx.x) * 4;
    if (i >= n) return;
    float4 v = *(const float4*)(src + i);
    ushort4 o;
    o.x = f2bf(v.x); o.y = f2bf(v.y); o.z = f2bf(v.z); o.w = f2bf(v.w);
    *(ushort4*)(dst + i) = o;
}

// fp32 -> bf16 hi + lo (x ~= hi + lo, residual ~2^-17 relative)
__global__ __launch_bounds__(256) void cvt_split_kernel(
    const float* __restrict__ src, ushort* __restrict__ hi, ushort* __restrict__ lo, int n)
{
    int i = (blockIdx.x * 256 + threadIdx.x) * 4;
    if (i >= n) return;
    float4 v = *(const float4*)(src + i);
    ushort4 h, l;
    h.x = f2bf(v.x); l.x = f2bf(v.x - bf2f(h.x));
    h.y = f2bf(v.y); l.y = f2bf(v.y - bf2f(h.y));
    h.z = f2bf(v.z); l.z = f2bf(v.z - bf2f(h.z));
    h.w = f2bf(v.w); l.w = f2bf(v.w - bf2f(h.w));
    *(ushort4*)(hi + i) = h;
    *(ushort4*)(lo + i) = l;
}

// ---------------------------------------------------------------------------
// K1: per-diff stats
// ---------------------------------------------------------------------------
__global__ __launch_bounds__(256) void traj_stats_kernel(
    const float* __restrict__ x, float* __restrict__ sbuf, float* __restrict__ invbuf)
{
    const int wave = threadIdx.x >> 6;
    const int lane = threadIdx.x & 63;
    const int row  = blockIdx.x * 4 + wave;
    const int NR = NB * (SEQ - 1);
    if (row >= NR) return;
    const int b = row / (SEQ - 1);
    const int j = row - b * (SEQ - 1);
    const float* x0 = x + ((size_t)(b * SEQ + j)) * DIM;
    const float* x1 = x0 + DIM;
    float sum = 0.f;
    #pragma unroll
    for (int q = 0; q < 4; ++q) {
        int idx = q * 256 + lane * 4;
        float4 a = *(const float4*)(x0 + idx);
        float4 c = *(const float4*)(x1 + idx);
        float dx = c.x-a.x, dy = c.y-a.y, dz = c.z-a.z, dw = c.w-a.w;
        sum += dx*dx + dy*dy + dz*dz + dw*dw;
    }
    #pragma unroll
    for (int off = 32; off > 0; off >>= 1) sum += __shfl_down(sum, off);
    if (lane == 0) {
        float mag = sqrtf(sum);
        sbuf[row]   = tanhf(mag);
        invbuf[row] = 1.0f / fmaxf(mag, 1e-8f);
    }
}

// ---------------------------------------------------------------------------
// K2: traj combine (window <= 8)
// ---------------------------------------------------------------------------
__global__ __launch_bounds__(256) void traj_kernel(
    const float* __restrict__ x, const float* __restrict__ sbuf,
    const float* __restrict__ invbuf, float* __restrict__ traj_out)
{
    const int bp = blockIdx.x;
    const int b  = bp >> 11;
    const int p  = bp & (SEQ - 1);
    int ws = p - 8; if (ws < 0) ws = 0;
    const int wlen = p - ws;
    const float wsz = (float)((p - ws) > 1 ? (p - ws) : 1);
    const int base = b * (SEQ - 1) + ws;

    float Z = 0.f;
    for (int t = 0; t < wlen; ++t)
        Z += sbuf[base + t] * ((float)(t + 1) / wsz);
    const float scale = 1.0f / fmaxf(Z, 1e-8f);

    const int d0 = threadIdx.x * 4;
    const float* xb = x + ((size_t)(b * SEQ + ws)) * DIM + d0;
    float4 prev = *(const float4*)xb;
    float4 acc = make_float4(0.f,0.f,0.f,0.f);
    for (int t = 0; t < wlen; ++t) {
        xb += DIM;
        float4 cur = *(const float4*)xb;
        float cc = sbuf[base + t] * ((float)(t + 1) / wsz) * invbuf[base + t] * scale;
        acc.x += cc * (cur.x - prev.x);
        acc.y += cc * (cur.y - prev.y);
        acc.z += cc * (cur.z - prev.z);
        acc.w += cc * (cur.w - prev.w);
        prev = cur;
    }
    *(float4*)(traj_out + (size_t)bp * DIM + d0) = acc;
}

// ---------------------------------------------------------------------------
// MFMA bf16 GEMM, m97 structure: C[M,N] = A[M,1024] @ B[N,1024]^T.
// 128x128 tile, BK=32, 4 waves 2x2, each wave 64x64 via 4x4 of 16x16x32.
// SPLIT=1: A ~= Ah+Al, B ~= Bh+Bl; C = Ah·Bh + Ah·Bl + Al·Bh (fp32-ish).
// EPI=0: fp32 store to cout (ldc).
// EPI=2 (v^T): bf16 store to qwb[b][m][token&2047]  (vbt layout [B,1024,S]).
// EPI=3 (q/k): bf16 head-major store: n<1024 -> qwb, else kwb,
//              layout [(b*NH+h)*SEQ + s]*64 + d.
// ---------------------------------------------------------------------------
template<int SPLIT, int EPI>
__global__ __launch_bounds__(256) void mfma_gemm(
    const ushort* __restrict__ Ah, const ushort* __restrict__ Al,
    const ushort* __restrict__ Bh, const ushort* __restrict__ Bl,
    float* __restrict__ cout, int ldc,
    ushort* __restrict__ qwb, ushort* __restrict__ kwb)
{
    constexpr int SMEM = SPLIT ? 32768 : 16384;
    __shared__ char smem[SMEM];
    const int tid = threadIdx.x;
    const int l = tid & 63;
    const int w = tid >> 6;
    const int wm = w >> 1, wn = w & 1;
    const int n0 = blockIdx.x * 128;
    const int m0 = blockIdx.y * 128;

    char* a_h = smem;
    char* b_h = smem + 8192;
    char* a_l = smem + 16384;
    char* b_l = smem + 24576;

    const int srow = 32 * w + (l >> 2);
    const int scol = (l & 3) * 8;
    const ushort* Ahg = Ah + (size_t)(m0 + srow) * 1024 + scol;
    const ushort* Bhg = Bh + (size_t)(n0 + srow) * 1024 + scol;
    const ushort* Alg = SPLIT ? Al + (size_t)(m0 + srow) * 1024 + scol : nullptr;
    const ushort* Blg = SPLIT ? Bl + (size_t)(n0 + srow) * 1024 + scol : nullptr;

    floatx4 acc[4][4] = {};
    const int fr = l & 15;
    const int fq = (l >> 4) * 16;

    for (int kb = 0; kb < 1024; kb += 32) {
        if (kb) __syncthreads();
        gload16(Ahg + kb,             a_h + w*2048);
        gload16(Ahg + kb + 16*1024,   a_h + w*2048 + 1024);
        gload16(Bhg + kb,             b_h + w*2048);
        gload16(Bhg + kb + 16*1024,   b_h + w*2048 + 1024);
        if (SPLIT) {
            gload16(Alg + kb,           a_l + w*2048);
            gload16(Alg + kb + 16*1024, a_l + w*2048 + 1024);
            gload16(Blg + kb,           b_l + w*2048);
            gload16(Blg + kb + 16*1024, b_l + w*2048 + 1024);
        }
        __syncthreads();
        short8 fah[4], fbh[4], fal[4], fbl[4];
        #pragma unroll
        for (int t = 0; t < 4; ++t) {
            fah[t] = *(const short8*)(a_h + ((wm*64 + t*16 + fr) << 6) + fq);
            fbh[t] = *(const short8*)(b_h + ((wn*64 + t*16 + fr) << 6) + fq);
            if (SPLIT) {
                fal[t] = *(const short8*)(a_l + ((wm*64 + t*16 + fr) << 6) + fq);
                fbl[t] = *(const short8*)(b_l + ((wn*64 + t*16 + fr) << 6) + fq);
            }
        }
        #pragma unroll
        for (int it = 0; it < 4; ++it)
            #pragma unroll
            for (int jt = 0; jt < 4; ++jt) {
                acc[it][jt] = __builtin_amdgcn_mfma_f32_16x16x32_bf16(
                    fah[it], fbh[jt], acc[it][jt], 0, 0, 0);
                if (SPLIT) {
                    acc[it][jt] = __builtin_amdgcn_mfma_f32_16x16x32_bf16(
                        fah[it], fbl[jt], acc[it][jt], 0, 0, 0);
                    acc[it][jt] = __builtin_amdgcn_mfma_f32_16x16x32_bf16(
                        fal[it], fbh[jt], acc[it][jt], 0, 0, 0);
                }
            }
    }

    const int row0 = (l >> 4) * 4;   // C: row=(l>>4)*4+reg, col=l&15
    const int col  = l & 15;

    if (EPI == 0) {
        #pragma unroll
        for (int it = 0; it < 4; ++it)
            #pragma unroll
            for (int jt = 0; jt < 4; ++jt)
                #pragma unroll
                for (int r = 0; r < 4; ++r) {
                    int gm = m0 + wm*64 + it*16 + row0 + r;
                    int gn = n0 + wn*64 + jt*16 + col;
                    cout[(size_t)gm * ldc + gn] = acc[it][jt][r];
                }
    } else if (EPI == 2) {
        // transposed v store: rows m = h*64+d, cols n = token
        #pragma unroll
        for (int it = 0; it < 4; ++it)
            #pragma unroll
            for (int jt = 0; jt < 4; ++jt)
                #pragma unroll
                for (int r = 0; r < 4; ++r) {
                    int md = m0 + wm*64 + it*16 + row0 + r;
                    int t  = n0 + wn*64 + jt*16 + col;
                    int bb = t >> 11, ss = t & (SEQ - 1);
                    qwb[((size_t)bb << 21) + (size_t)md * SEQ + ss] = f2bf(acc[it][jt][r]);
                }
    } else {
        // q/k bf16 head-major store
        ushort* obuf = (n0 < 1024) ? qwb : kwb;
        const int nb = n0 & 1023;
        #pragma unroll
        for (int it = 0; it < 4; ++it)
            #pragma unroll
            for (int jt = 0; jt < 4; ++jt)
                #pragma unroll
                for (int r = 0; r < 4; ++r) {
                    int gm = m0 + wm*64 + it*16 + row0 + r;     // token
                    int gn = nb + wn*64 + jt*16 + col;          // h*64+d
                    int hh = gn >> 6, d = gn & 63;
                    int bb = gm >> 11, ss = gm & (SEQ - 1);
                    obuf[(((size_t)(bb*NH + hh))*SEQ + ss)*64 + d] = f2bf(acc[it][jt][r]);
                }
    }
}

// ---------------------------------------------------------------------------
// Splat weights from bf16 q (or k), head-major [(b*NH+h)*SEQ+s]*64.
// One block = 256 consecutive tokens of one (b,h); one thread per token.
// wout[(b*NH+h)*SEQ+s]*16+sp = exp(-0.5*|q-c_sp|^2 / s_sp^2) * sigmoid(amp_sp)
// ---------------------------------------------------------------------------
__global__ __launch_bounds__(256) void splat_kernel(
    const ushort* __restrict__ qk, ushort* __restrict__ wout,
    const float* __restrict__ centers, const float* __restrict__ lscales,
    const float* __restrict__ amps)
{
    __shared__ float Cs[16*64];
    __shared__ float Pr[48];          // [0,16): -0.5/s2, [16,32): amp, [32,48): cn
    const int tid = threadIdx.x;
    const int bh  = blockIdx.x >> 3;
    const int h   = bh & 15;
    const int s   = (blockIdx.x & 7) * 256 + tid;
    {
        float4 c4 = *(const float4*)(centers + (size_t)h*1024 + tid*4);
        *(float4*)(Cs + tid*4) = c4;
    }
    if (tid < 16) {
        float s2 = __expf(2.f * lscales[h*16 + tid]);
        Pr[tid]      = -0.5f / s2;
        Pr[16 + tid] = 1.f / (1.f + __expf(-amps[h*16 + tid]));
        const float* cp = centers + ((size_t)h*16 + tid)*64;
        float cn = 0.f;
        for (int i = 0; i < 64; ++i) cn += cp[i]*cp[i];
        Pr[32 + tid] = cn;
    }
    __syncthreads();

    float q[64];
    const ushort* qp = qk + ((size_t)bh*SEQ + s)*64;
    #pragma unroll
    for (int i = 0; i < 8; ++i) {
        short8 v = *(const short8*)(qp + i*8);
        #pragma unroll
        for (int j = 0; j < 8; ++j) q[i*8+j] = bf2f((ushort)v[j]);
    }
    float tn = 0.f;
    #pragma unroll
    for (int i = 0; i < 64; ++i) tn = fmaf(q[i], q[i], tn);

    ushort o16[16];
    #pragma unroll 4
    for (int sp = 0; sp < 16; ++sp) {
        const float* cp = Cs + sp*64;
        float cr = 0.f;
        #pragma unroll
        for (int i = 0; i < 64; ++i) cr = fmaf(q[i], cp[i], cr);
        float dq = tn - 2.f*cr + Pr[32 + sp];
        o16[sp] = f2bf(__expf(dq * Pr[sp]) * Pr[16 + sp]);
    }
    ushort* op = wout + ((size_t)bh*SEQ + s)*16;
    *(short8*)(op)     = *(short8*)(o16);
    *(short8*)(op + 8) = *(short8*)(o16 + 8);
}

// ---------------------------------------------------------------------------
// MFMA flash attention (unchanged from round 4).
// ---------------------------------------------------------------------------
__global__ __launch_bounds__(256) void attn_kernel(
    const ushort* __restrict__ qw, const ushort* __restrict__ kw,
    const ushort* __restrict__ vbt, ushort* __restrict__ hoh, ushort* __restrict__ hol)
{
    __shared__ ushort KWs[64*16];        // 2 KB  [key][16]
    __shared__ ushort VTs[64*64];        // 8 KB  [d][key blocks, xor-swizzled]
    __shared__ ushort Ps[4][16*64];      // 8 KB  per-wave P
    const int tid = threadIdx.x;
    const int l = tid & 63;
    const int w = tid >> 6;
    const int bh = blockIdx.y;
    const int b = bh >> 4;
    const int h = bh & 15;
    const int s0 = blockIdx.x * 64;
    const int qrow = l & 15;
    const int quad = l >> 4;

    short8 aq = {};
    if (l < 32)
        aq = *(const short8*)(qw + (((size_t)bh*SEQ) + s0 + w*16 + qrow)*16 + quad*8);

    const ushort* kwb = kw + ((size_t)bh*SEQ)*16;
    const ushort* vtb = vbt + ((size_t)(b*1024 + h*64))*SEQ;

    floatx4 accv[4] = {};
    floatx4 accz = {};
    floatx4 zero = {};
    short8 ones;
    #pragma unroll
    for (int i = 0; i < 8; ++i) ones[i] = (short)0x3F80;

    const int vd0 = w*2*8 + (l >> 3);
    const int vkb0 = (l & 7) ^ (vd0 & 7);
    const int vd1 = (w*2+1)*8 + (l >> 3);
    const int vkb1 = (l & 7) ^ (vd1 & 7);

    for (int jt = 0; jt < SEQ/64; ++jt) {
        const int j0 = jt * 64;
        if (jt) __syncthreads();
        if (w < 2)
            gload16(kwb + (size_t)(j0 + w*32)*16 + l*8, (char*)KWs + w*1024);
        gload16(vtb + (size_t)vd0*SEQ + j0 + vkb0*8, (char*)VTs + (w*2  )*1024);
        gload16(vtb + (size_t)vd1*SEQ + j0 + vkb1*8, (char*)VTs + (w*2+1)*1024);
        __syncthreads();

        floatx4 sc[4];
        #pragma unroll
        for (int kt = 0; kt < 4; ++kt) {
            short8 bk = {};
            if (l < 32)
                bk = *(const short8*)(KWs + (kt*16 + qrow)*16 + quad*8);
            sc[kt] = __builtin_amdgcn_mfma_f32_16x16x32_bf16(aq, bk, zero, 0, 0, 0);
        }
        ushort* Pw = Ps[w];
        #pragma unroll
        for (int kt = 0; kt < 4; ++kt)
            #pragma unroll
            for (int r = 0; r < 4; ++r) {
                float e = __expf(sc[kt][r]);
                int q = quad*4 + r;
                int key = kt*16 + qrow;
                Pw[q*64 + ((((key>>3) ^ (q&7)) << 3) | (key & 7))] =
                    (ushort)(__float_as_uint(e) >> 16);
            }
        #pragma unroll
        for (int kc = 0; kc < 2; ++kc) {
            int kb = kc*4 + quad;
            short8 pa = *(const short8*)(Pw + qrow*64 + ((kb ^ (qrow & 7)) << 3));
            #pragma unroll
            for (int nt = 0; nt < 4; ++nt) {
                int d = nt*16 + qrow;
                short8 vb8 = *(const short8*)(VTs + d*64 + ((kb ^ (d & 7)) << 3));
                accv[nt] = __builtin_amdgcn_mfma_f32_16x16x32_bf16(pa, vb8, accv[nt], 0, 0, 0);
            }
            accz = __builtin_amdgcn_mfma_f32_16x16x32_bf16(pa, ones, accz, 0, 0, 0);
        }
    }

    #pragma unroll
    for (int r = 0; r < 4; ++r) {
        float inv = 1.0f / accz[r];
        int s = s0 + w*16 + quad*4 + r;
        size_t base = ((size_t)(b*SEQ + s))*1024 + h*64;
        #pragma unroll
        for (int nt = 0; nt < 4; ++nt) {
            float val = accv[nt][r] * inv;
            ushort hi = f2bf(val);
            ushort lo = f2bf(val - bf2f(hi));
            hoh[base + nt*16 + qrow] = hi;
            hol[base + nt*16 + qrow] = lo;
        }
    }
}

// ---------------------------------------------------------------------------
extern "C" void kernel_launch(void* const* d_in, const int* in_sizes, int n_in,
                              void* d_out, int out_size, void* d_ws, size_t ws_size,
                              hipStream_t stream)
{
    const float* x       = (const float*)d_in[0];
    const float* qkv_w   = (const float*)d_in[1];
    const float* out_w   = (const float*)d_in[2];
    const float* centers = (const float*)d_in[3];
    const float* lscales = (const float*)d_in[4];
    const float* amps    = (const float*)d_in[5];
    float* out  = (float*)d_out;                      // [B,S,D]
    float* traj = out + (size_t)NB*SEQ*DIM;           // [B,S,D]

    char* wsb = (char*)d_ws;                          // 40.03 MB total
    ushort* xh   = (ushort*)(wsb);                    // [0,8) MB  bf16 x hi
    ushort* xl   = (ushort*)(wsb + (8u<<20));         // [8,16) MB bf16 x lo
    ushort* wh   = (ushort*)(wsb + (16u<<20));        // [16,22) MB qkv_w hi (3072x1024)
    ushort* wlv  = (ushort*)(wsb + (22u<<20));        // [22,24) MB v-weight lo
    ushort* vbt  = (ushort*)(wsb + (24u<<20));        // [24,32) MB v^T bf16 [B,1024,S]
    float*  sbuf = (float*)(wsb + (40u<<20));         // 16 KB
    float*  invb = sbuf + 4096;                       // 16 KB
    // aliases (regions dead by the time they're written):
    ushort* qbuf = xl;                                // q bf16 head-major (xl dead after vgemm)
    ushort* kbuf = (ushort*)(wsb + (32u<<20));        // k bf16 head-major, [32,40) free
    ushort* qwbh = wlv;                               // splat-q out (after vgemm)
    ushort* kwbh = wh + 2048*1024;                    // wh [20,22) dead after vgemm
    ushort* owh  = wh;                                // wh [16,18) dead after qkgemm
    ushort* owl  = wh + 1048576;                      // wh [18,20)
    ushort* hoh  = xh;                                // after qkgemm (attn writes)
    ushort* hol  = xl;                                // after splat-q consumed qbuf

    cvt_split_kernel<<<4096, 256, 0, stream>>>(x, xh, xl, 4194304);
    cvt_hi_kernel<<<3072, 256, 0, stream>>>(qkv_w, wh, 3145728);
    cvt_split_kernel<<<1024, 256, 0, stream>>>(qkv_w + 2097152, wh + 2097152, wlv, 1048576);
    traj_stats_kernel<<<1024, 256, 0, stream>>>(x, sbuf, invb);
    traj_kernel<<<NB*SEQ, 256, 0, stream>>>(x, sbuf, invb, traj);
    // v^T = Wv @ x^T  (split, bf16 transposed store [B,1024,S])
    mfma_gemm<1,2><<<dim3(32, 8), 256, 0, stream>>>(
        wh + 2048*1024, wlv, xh, xl, nullptr, 0, vbt, nullptr);
    // q,k projection (plain bf16), head-major bf16 out
    mfma_gemm<0,3><<<dim3(16, 32), 256, 0, stream>>>(
        xh, nullptr, wh, nullptr, nullptr, 0, qbuf, kbuf);
    // splat weights
    splat_kernel<<<256, 256, 0, stream>>>(qbuf, qwbh, centers, lscales, amps);
    splat_kernel<<<256, 256, 0, stream>>>(kbuf, kwbh, centers, lscales, amps);
    cvt_split_kernel<<<1024, 256, 0, stream>>>(out_w, owh, owl, 1048576);
    attn_kernel<<<dim3(32, 32), 256, 0, stream>>>(qwbh, kwbh, vbt, hoh, hol);
    // out = ho @ out_w^T  (split, fp32 out)
    mfma_gemm<1,0><<<dim3(8, 32), 256, 0, stream>>>(
        hoh, hol, owh, owl, out, 1024, nullptr, nullptr);
}